// Round 10
// baseline (202.103 us; speedup 1.0000x reference)
//
#include <hip/hip_runtime.h>
#include <math.h>
#include <string.h>

#define CDIM 64
#define LDSW 72   // row stride in bf16 elems (144 B): b128 frag reads conflict-free (stride 36 dw)
#define DEG  5    // Chebyshev tail on [1,7.5] ~5.6e-3; Paterson-Stockmeyer s=2 -> 3 matmuls
#define GRID 1024 // 4 blocks/CU x 256 CU persistent grid

struct Coefs { float a[DEG + 1]; float cc; float inv_h; };

typedef __attribute__((ext_vector_type(8)))  short short8;      // 8 bf16 = 4 VGPRs (MFMA A/B frag)
typedef __attribute__((ext_vector_type(16))) float floatx16;    // MFMA C/D
typedef __attribute__((ext_vector_type(4)))  float floatx4;     // packed global I/O
typedef __attribute__((ext_vector_type(4)))  unsigned short ushort4v;  // packed LDS I/O

// f32 -> bf16 round-to-nearest-even (bit trick, ~2^-9 max rel err).
__device__ __forceinline__ unsigned short f2bf_rn(float x) {
  const unsigned u = __builtin_bit_cast(unsigned, x);
  return (unsigned short)((u + 0x7FFFu + ((u >> 16) & 1u)) >> 16);
}
__device__ __forceinline__ float bf2f(unsigned short s) {
  return __builtin_bit_cast(float, ((unsigned)s) << 16);
}

struct Frags  { short8 h[4]; short8 l[4]; };   // hi+lo fragments = 32 VGPRs
struct FragsH { short8 h[4]; };                // hi-only fragments = 16 VGPRs

__device__ __forceinline__ void load_frags(const unsigned short* __restrict__ Ph,
                                           const unsigned short* __restrict__ Pl,
                                           int row, int ko, Frags* f) {
#pragma unroll
  for (int kk = 0; kk < 4; ++kk) {
    f->h[kk] = *(const short8*)(Ph + row * LDSW + kk * 16 + ko);
    f->l[kk] = *(const short8*)(Pl + row * LDSW + kk * 16 + ko);
  }
}

__device__ __forceinline__ void load_frags_h(const unsigned short* __restrict__ Ph,
                                             int row, int ko, FragsH* f) {
#pragma unroll
  for (int kk = 0; kk < 4; ++kk)
    f->h[kk] = *(const short8*)(Ph + row * LDSW + kk * 16 + ko);
}

// Single-chain h*h 32x32 tile product (downstream matmuls: dropped l-terms
// are ~2^-9-relative, scaled by small coefficients -> ~1e-3 output error).
__device__ __forceinline__ floatx16 mm_h(const FragsH& a, const FragsH& b) {
  floatx16 c;
#pragma unroll
  for (int i = 0; i < 16; ++i) c[i] = 0.0f;
#pragma unroll
  for (int kk = 0; kk < 4; ++kk)
    c = __builtin_amdgcn_mfma_f32_32x32x16_bf16(a.h[kk], b.h[kk], c, 0, 0, 0);
  return c;
}

// R10: persistent 2-barrier pipeline (R4 retried on the slim 52-VGPR baseline).
// Per-iteration schedule:
//   P1: fa<-A, mm1 (fb slab-wise), fold accM2; issue xpf = X(next); M2 -> Ch
//   B2  (M2 published; A(i) reads retired -> A overwritable)
//   P2: fm2<-Ch; accT = M1*M2; rM1B+stage A(next) from xpf; fold Q1 -> Dh
//   B3  (Q1 published; Ch reads retired)
//   P3: fq1<-Dh; out = Q1*M2 + a1*rM1A + a0*I -> Y; rM1A = rM1B
// P3 -> next P1 needs NO barrier: P1' writes Ch (last read at B3, fm2 cached
// in regs), reads A (written P2, ordered by B3). Stage-load latency hides
// under mm1+epilogue; store latency hides under next P1.
// Audited steady-state peak ~106 regs < 128 (4-wave cap). Spill canary:
// WRITE_SIZE > ~105 MB -> drop accM2 carry next round.
__global__ void __launch_bounds__(256, 4)
logm_kernel(const float* __restrict__ X, float* __restrict__ Y, int nmat, Coefs cf) {
  // Buffers (all TRANSPOSED [col][row]; symmetric => same data):
  // A(hi+lo) = M1(i) then M1(i+1), Ch = M2, Dh = Q1. 4 x 9216 B = 36,864 B.
  __shared__ __align__(16) unsigned short Ah[CDIM * LDSW], Al[CDIM * LDSW];
  __shared__ __align__(16) unsigned short Ch[CDIM * LDSW];
  __shared__ __align__(16) unsigned short Dh[CDIM * LDSW];

  const int tid  = threadIdx.x;
  const int lane = tid & 63;
  const int w    = tid >> 6;

  const int R     = (w >> 1) * 32;
  const int Cc    = (w & 1) * 32;
  const int l31   = lane & 31;
  const int half  = lane >> 5;
  const int arow  = R + l31;
  const int brow  = Cc + l31;
  const int ko    = half * 8;
  const int col   = Cc + l31;
  const int base0 = R + 4 * half;   // quad q covers rows base0+8q .. +3
  // C/D layout: r=4q+j -> row = base0 + 8q + j, col = col  [verified m74/m101]

  int m = blockIdx.x;
  if (m >= nmat) return;           // uniform, before any barrier

  // ---- prologue: stage M1(first) -> A hi/lo transposed-packed; keep rM1A ----
  float rM1A[16];
  {
    const float* __restrict__ Xc = X + (size_t)m * (CDIM * CDIM) + col * CDIM;
#pragma unroll
    for (int q = 0; q < 4; ++q) {
      const int br = base0 + 8 * q;
      const floatx4 xv = *(const floatx4*)(Xc + br);
      ushort4v hv, lv;
#pragma unroll
      for (int j = 0; j < 4; ++j) {
        float x = xv[j];
        if (br + j == col) x -= cf.cc;
        const float t = x * cf.inv_h;
        rM1A[4 * q + j] = t;
        const unsigned short hu = f2bf_rn(t);
        hv[j] = hu;
        lv[j] = f2bf_rn(t - bf2f(hu));
      }
      const int idxT = col * LDSW + br;
      *(ushort4v*)(Ah + idxT) = hv;
      *(ushort4v*)(Al + idxT) = lv;
    }
  }
  __syncthreads();   // B1: M1(first) published

  for (; m < nmat; m += GRID) {
    const int mn = m + GRID;
    const bool has_next = (mn < nmat);   // block-uniform

    // ---- P1: mm1: M2 = M1*M1 (full compensation, 2 acc chains; fb slab-wise) ----
    Frags fa;
    load_frags(Ah, Al, arow, ko, &fa);
    floatx16 c1, c2;
#pragma unroll
    for (int i = 0; i < 16; ++i) { c1[i] = 0.0f; c2[i] = 0.0f; }
#pragma unroll
    for (int kk = 0; kk < 4; ++kk) {
      const short8 fbh = *(const short8*)(Ah + brow * LDSW + kk * 16 + ko);
      const short8 fbl = *(const short8*)(Al + brow * LDSW + kk * 16 + ko);
      c1 = __builtin_amdgcn_mfma_f32_32x32x16_bf16(fa.h[kk], fbh, c1, 0, 0, 0);
      c2 = __builtin_amdgcn_mfma_f32_32x32x16_bf16(fa.h[kk], fbl, c2, 0, 0, 0);
      c2 = __builtin_amdgcn_mfma_f32_32x32x16_bf16(fa.l[kk], fbh, c2, 0, 0, 0);
    }
    // issue next-matrix loads (fa.l/fb dead soon; ~1500cy of cover to use in P2)
    floatx4 xpf[4];
    if (has_next) {
      const float* __restrict__ Xn = X + (size_t)mn * (CDIM * CDIM) + col * CDIM;
#pragma unroll
      for (int q = 0; q < 4; ++q) xpf[q] = *(const floatx4*)(Xn + base0 + 8 * q);
    }
    floatx16 accM2;
#pragma unroll
    for (int i = 0; i < 16; ++i) accM2[i] = c1[i] + c2[i];
#pragma unroll
    for (int q = 0; q < 4; ++q) {
      ushort4v hv;
#pragma unroll
      for (int j = 0; j < 4; ++j) hv[j] = f2bf_rn(accM2[4 * q + j]);
      *(ushort4v*)(Ch + col * LDSW + base0 + 8 * q) = hv;   // M2 transposed-packed
    }
    __syncthreads();   // B2: M2 published; A(i) reads retired

    // ---- P2: T = M1*M2 (fa.h reused); stage A(next); Q1 -> Dh ----
    FragsH fah, fm2;
#pragma unroll
    for (int kk = 0; kk < 4; ++kk) fah.h[kk] = fa.h[kk];
    load_frags_h(Ch, brow, ko, &fm2);    // M2 B-operand via symmetry; kept for P3
    floatx16 accT = mm_h(fah, fm2);
    float rM1B[16];
    if (has_next) {                      // block-uniform
#pragma unroll
      for (int q = 0; q < 4; ++q) {
        const int br = base0 + 8 * q;
        ushort4v hv, lv;
#pragma unroll
        for (int j = 0; j < 4; ++j) {
          float x = xpf[q][j];
          if (br + j == col) x -= cf.cc;
          const float t = x * cf.inv_h;
          rM1B[4 * q + j] = t;
          const unsigned short hu = f2bf_rn(t);
          hv[j] = hu;
          lv[j] = f2bf_rn(t - bf2f(hu));
        }
        const int idxT = col * LDSW + br;
        *(ushort4v*)(Ah + idxT) = hv;    // A(next) over A(cur): safe after B2
        *(ushort4v*)(Al + idxT) = lv;
      }
    }
#pragma unroll
    for (int q = 0; q < 4; ++q) {
      const int br = base0 + 8 * q;
      ushort4v hv;
#pragma unroll
      for (int j = 0; j < 4; ++j) {
        const int r = 4 * q + j;
        float v = cf.a[5] * accT[r] + cf.a[4] * accM2[r] + cf.a[3] * rM1A[r];
        if (br + j == col) v += cf.a[2];
        hv[j] = f2bf_rn(v);
      }
      *(ushort4v*)(Dh + col * LDSW + br) = hv;   // Q1 transposed-packed
    }
    __syncthreads();   // B3: Q1 + A(next) published; Ch reads retired

    // ---- P3: out = Q1*M2 + a1*rM1A + a0*I -> global (dwordx4, un-transposes) ----
    FragsH fq1;
    load_frags_h(Dh, arow, ko, &fq1);
    floatx16 accF = mm_h(fq1, fm2);
    {
      float* __restrict__ Yc = Y + (size_t)m * (CDIM * CDIM) + col * CDIM;
#pragma unroll
      for (int q = 0; q < 4; ++q) {
        const int br = base0 + 8 * q;
        floatx4 pv;
#pragma unroll
        for (int j = 0; j < 4; ++j) {
          const int r = 4 * q + j;
          float p = accF[r] + cf.a[1] * rM1A[r];
          if (br + j == col) p += cf.a[0];
          pv[j] = p;
        }
        *(floatx4*)(Yc + br) = pv;       // store drains under next P1
      }
    }
    if (has_next) {
#pragma unroll
      for (int r = 0; r < 16; ++r) rM1A[r] = rM1B[r];
    }
    // no barrier: next P1 writes Ch (reads retired at B3), reads A (published B3)
  }
}

extern "C" void kernel_launch(void* const* d_in, const int* in_sizes, int n_in,
                              void* d_out, int out_size, void* d_ws, size_t ws_size,
                              hipStream_t stream) {
  const float* X = (const float*)d_in[0];
  float* Y = (float*)d_out;
  const int nmat = in_sizes[0] / (CDIM * CDIM);

  // Chebyshev coefficients of log on [lo,hi] -> monomial basis in t=(x-cc)/hh.
  // Analytic: log(cc+hh*t) = log(A) - 2*sum_k z^k/k T_k(t),  z=(-cc+sqrt(cc^2-hh^2))/hh
  Coefs cf;
  {
    const double lo = 1.0, hi = 7.5;
    const double cc = 0.5 * (lo + hi), hh = 0.5 * (hi - lo);
    const double s  = sqrt(cc * cc - hh * hh);
    const double z  = (-cc + s) / hh;
    const double A  = 0.5 * (cc + s);
    double cheb[DEG + 1];
    cheb[0] = log(A);
    double zp = 1.0;
    for (int k = 1; k <= DEG; ++k) { zp *= z; cheb[k] = -2.0 * zp / (double)k; }
    double mono[DEG + 1], Tprev[DEG + 1], Tcur[DEG + 1];
    memset(mono, 0, sizeof(mono));
    memset(Tprev, 0, sizeof(Tprev));
    memset(Tcur, 0, sizeof(Tcur));
    Tprev[0] = 1.0; mono[0] += cheb[0];
    Tcur[1]  = 1.0; mono[1] += cheb[1];
    for (int k = 2; k <= DEG; ++k) {
      double Tn[DEG + 1];
      memset(Tn, 0, sizeof(Tn));
      for (int j = 0; j <= k; ++j) {
        double v = -Tprev[j];
        if (j > 0) v += 2.0 * Tcur[j - 1];
        Tn[j] = v;
      }
      for (int j = 0; j <= k; ++j) mono[j] += cheb[k] * Tn[j];
      for (int j = 0; j <= DEG; ++j) { Tprev[j] = Tcur[j]; Tcur[j] = Tn[j]; }
    }
    for (int i = 0; i <= DEG; ++i) cf.a[i] = (float)mono[i];
    cf.cc = (float)cc; cf.inv_h = (float)(1.0 / hh);
  }

  const int nblk = nmat < GRID ? nmat : GRID;
  dim3 grid(nblk), block(256);
  hipLaunchKernelGGL(logm_kernel, grid, block, 0, stream, X, Y, nmat, cf);
}

// Round 11
// 185.633 us; speedup vs baseline: 1.0887x; 1.0887x over previous
//
#include <hip/hip_runtime.h>
#include <hip/hip_bf16.h>
#include <math.h>
#include <string.h>

#define CDIM 64
#define LDSW 72   // row stride in bf16 elems (144 B): b128 frag reads conflict-free (stride 36 dw)
#define DEG  5    // Chebyshev tail on [1,7.5] ~5.6e-3; Paterson-Stockmeyer s=2 -> 3 matmuls
#define GRID 1024 // 4 blocks/CU x 256 CU resident grid (grid-stride, no prefetch state)

struct Coefs { float a[DEG + 1]; float cc; float inv_h; };

typedef __attribute__((ext_vector_type(8)))  short short8;      // 8 bf16 = 4 VGPRs (MFMA A/B frag)
typedef __attribute__((ext_vector_type(16))) float floatx16;    // MFMA C/D
typedef __attribute__((ext_vector_type(4)))  float floatx4;     // packed global I/O
typedef __attribute__((ext_vector_type(4)))  unsigned short ushort4v;  // packed LDS I/O

// f32 -> bf16 via HW convert (RNE). Compiler pairs adjacent casts into
// v_cvt_pk_bf16_f32 -- ~1 VALU per 1-2 conversions vs ~4 for the bit-trick
// (R10 counter audit: conversions were ~350 of ~756 VALU instrs/wave).
__device__ __forceinline__ unsigned short f2bf_rn(float x) {
  const __hip_bfloat16 b = __float2bfloat16(x);
  return __builtin_bit_cast(unsigned short, b);
}
__device__ __forceinline__ float bf2f(unsigned short s) {
  return __builtin_bit_cast(float, ((unsigned)s) << 16);
}

struct Frags  { short8 h[4]; short8 l[4]; };   // hi+lo fragments = 32 VGPRs
struct FragsH { short8 h[4]; };                // hi-only fragments = 16 VGPRs

__device__ __forceinline__ void load_frags(const unsigned short* __restrict__ Ph,
                                           const unsigned short* __restrict__ Pl,
                                           int row, int ko, Frags* f) {
#pragma unroll
  for (int kk = 0; kk < 4; ++kk) {
    f->h[kk] = *(const short8*)(Ph + row * LDSW + kk * 16 + ko);
    f->l[kk] = *(const short8*)(Pl + row * LDSW + kk * 16 + ko);
  }
}

__device__ __forceinline__ void load_frags_h(const unsigned short* __restrict__ Ph,
                                             int row, int ko, FragsH* f) {
#pragma unroll
  for (int kk = 0; kk < 4; ++kk)
    f->h[kk] = *(const short8*)(Ph + row * LDSW + kk * 16 + ko);
}

// Single-chain h*h 32x32 tile product (downstream matmuls: dropped l-terms
// are ~2^-9-relative, scaled by small coefficients -> ~1e-3 output error).
__device__ __forceinline__ floatx16 mm_h(const FragsH& a, const FragsH& b) {
  floatx16 c;
#pragma unroll
  for (int i = 0; i < 16; ++i) c[i] = 0.0f;
#pragma unroll
  for (int kk = 0; kk < 4; ++kk)
    c = __builtin_amdgcn_mfma_f32_32x32x16_bf16(a.h[kk], b.h[kk], c, 0, 0, 0);
  return c;
}

// R11: grid-stride persistence with the EXACT R9 per-iteration body.
// R10's failure was the prefetch state (xpf+rM1B, +32 regs -> spill), not
// persistence: this version carries ZERO extra live state across iterations.
// Motivation: measured occupancy 33-40% vs 50% steady-state ceiling -- the
// deficit is dispatch gaps between 6400 short-lived blocks. 1024 resident
// blocks x 6-7 iterations amortize launch/setup.
// Cross-iteration hazards: A-writes (stage i+1) vs fa-reads (P1 i) and
// Dh-writes (P2 i+1) vs fq1-reads (mm3 i) are >=2 collective barriers apart;
// __syncthreads' lgkm drain retires each wave's reads before the barrier. Safe.
__global__ void __launch_bounds__(256, 4)
logm_kernel(const float* __restrict__ X, float* __restrict__ Y, int nmat, Coefs cf) {
  // Buffers (all TRANSPOSED [col][row]; symmetric => same data):
  // A(hi+lo) = M1, Ch = M2, Dh = Q1. 4 x 9216 B = 36,864 B -> 4 blocks/CU.
  __shared__ __align__(16) unsigned short Ah[CDIM * LDSW], Al[CDIM * LDSW];
  __shared__ __align__(16) unsigned short Ch[CDIM * LDSW];
  __shared__ __align__(16) unsigned short Dh[CDIM * LDSW];

  const int tid  = threadIdx.x;
  const int lane = tid & 63;
  const int w    = tid >> 6;

  const int R     = (w >> 1) * 32;
  const int Cc    = (w & 1) * 32;
  const int l31   = lane & 31;
  const int half  = lane >> 5;
  const int arow  = R + l31;
  const int brow  = Cc + l31;
  const int ko    = half * 8;
  const int col   = Cc + l31;
  const int base0 = R + 4 * half;   // quad q covers rows base0+8q .. +3
  // C/D layout: r=4q+j -> row = base0 + 8q + j, col = col  [verified m74/m101]

  for (int m = blockIdx.x; m < nmat; m += GRID) {

    // ---- stage: read X column-wise (dwordx4, symmetric => same data),
    //      M1 -> A hi/lo transposed-packed (b64 per quad); keep t in rM1 ----
    float rM1[16];
    {
      const float* __restrict__ Xc = X + (size_t)m * (CDIM * CDIM) + col * CDIM;
#pragma unroll
      for (int q = 0; q < 4; ++q) {
        const int br = base0 + 8 * q;
        const floatx4 xv = *(const floatx4*)(Xc + br);
        ushort4v hv, lv;
#pragma unroll
        for (int j = 0; j < 4; ++j) {
          float x = xv[j];
          if (br + j == col) x -= cf.cc;
          const float t = x * cf.inv_h;
          rM1[4 * q + j] = t;
          const unsigned short hu = f2bf_rn(t);
          hv[j] = hu;
          lv[j] = f2bf_rn(t - bf2f(hu));
        }
        const int idxT = col * LDSW + br;
        *(ushort4v*)(Ah + idxT) = hv;
        *(ushort4v*)(Al + idxT) = lv;
      }
    }
    __syncthreads();   // B1: M1 published (also orders stage-writes vs prior fa-reads)

    // ---- P1 / mm1: M2 = M1*M1 (full compensation, 2 acc chains; fb slab-wise) ----
    Frags fa;
    load_frags(Ah, Al, arow, ko, &fa);
    floatx16 c1, c2;
#pragma unroll
    for (int i = 0; i < 16; ++i) { c1[i] = 0.0f; c2[i] = 0.0f; }
#pragma unroll
    for (int kk = 0; kk < 4; ++kk) {
      const short8 fbh = *(const short8*)(Ah + brow * LDSW + kk * 16 + ko);
      const short8 fbl = *(const short8*)(Al + brow * LDSW + kk * 16 + ko);
      c1 = __builtin_amdgcn_mfma_f32_32x32x16_bf16(fa.h[kk], fbh, c1, 0, 0, 0);
      c2 = __builtin_amdgcn_mfma_f32_32x32x16_bf16(fa.h[kk], fbl, c2, 0, 0, 0);
      c2 = __builtin_amdgcn_mfma_f32_32x32x16_bf16(fa.l[kk], fbh, c2, 0, 0, 0);
    }
    floatx16 accM2;
#pragma unroll
    for (int i = 0; i < 16; ++i) accM2[i] = c1[i] + c2[i];
#pragma unroll
    for (int q = 0; q < 4; ++q) {
      ushort4v hv;
#pragma unroll
      for (int j = 0; j < 4; ++j) hv[j] = f2bf_rn(accM2[4 * q + j]);
      *(ushort4v*)(Ch + col * LDSW + base0 + 8 * q) = hv;   // M2 transposed-packed
    }
    __syncthreads();   // B2: M2 published; A reads retired

    // ---- P2: T = M1*M2 (fa.h reused); Q1 = a5*T + a4*accM2 + a3*rM1 + a2*I -> Dh ----
    FragsH fah, fm2;
#pragma unroll
    for (int kk = 0; kk < 4; ++kk) fah.h[kk] = fa.h[kk];
    load_frags_h(Ch, brow, ko, &fm2);    // M2 B-operand via symmetry; kept for mm3
    floatx16 accT = mm_h(fah, fm2);
#pragma unroll
    for (int q = 0; q < 4; ++q) {
      const int br = base0 + 8 * q;
      ushort4v hv;
#pragma unroll
      for (int j = 0; j < 4; ++j) {
        const int r = 4 * q + j;
        float v = cf.a[5] * accT[r] + cf.a[4] * accM2[r] + cf.a[3] * rM1[r];
        if (br + j == col) v += cf.a[2];
        hv[j] = f2bf_rn(v);
      }
      *(ushort4v*)(Dh + col * LDSW + br) = hv;   // Q1 transposed-packed
    }
    __syncthreads();   // B3: Q1 published; Ch reads retired

    // ---- mm3: out = Q1*M2 (h-only) + a1*rM1 + a0*I -> global (dwordx4) ----
    FragsH fq1;
    load_frags_h(Dh, arow, ko, &fq1);
    floatx16 accF = mm_h(fq1, fm2);
    {
      float* __restrict__ Yc = Y + (size_t)m * (CDIM * CDIM) + col * CDIM;
#pragma unroll
      for (int q = 0; q < 4; ++q) {
        const int br = base0 + 8 * q;
        floatx4 pv;
#pragma unroll
        for (int j = 0; j < 4; ++j) {
          const int r = 4 * q + j;
          float p = accF[r] + cf.a[1] * rM1[r];
          if (br + j == col) p += cf.a[0];
          pv[j] = p;
        }
        *(floatx4*)(Yc + br) = pv;
      }
    }
    // next iteration's B1 orders stage-writes after this mm3's Dh reads
  }
}

extern "C" void kernel_launch(void* const* d_in, const int* in_sizes, int n_in,
                              void* d_out, int out_size, void* d_ws, size_t ws_size,
                              hipStream_t stream) {
  const float* X = (const float*)d_in[0];
  float* Y = (float*)d_out;
  const int nmat = in_sizes[0] / (CDIM * CDIM);

  // Chebyshev coefficients of log on [lo,hi] -> monomial basis in t=(x-cc)/hh.
  // Analytic: log(cc+hh*t) = log(A) - 2*sum_k z^k/k T_k(t),  z=(-cc+sqrt(cc^2-hh^2))/hh
  Coefs cf;
  {
    const double lo = 1.0, hi = 7.5;
    const double cc = 0.5 * (lo + hi), hh = 0.5 * (hi - lo);
    const double s  = sqrt(cc * cc - hh * hh);
    const double z  = (-cc + s) / hh;
    const double A  = 0.5 * (cc + s);
    double cheb[DEG + 1];
    cheb[0] = log(A);
    double zp = 1.0;
    for (int k = 1; k <= DEG; ++k) { zp *= z; cheb[k] = -2.0 * zp / (double)k; }
    double mono[DEG + 1], Tprev[DEG + 1], Tcur[DEG + 1];
    memset(mono, 0, sizeof(mono));
    memset(Tprev, 0, sizeof(Tprev));
    memset(Tcur, 0, sizeof(Tcur));
    Tprev[0] = 1.0; mono[0] += cheb[0];
    Tcur[1]  = 1.0; mono[1] += cheb[1];
    for (int k = 2; k <= DEG; ++k) {
      double Tn[DEG + 1];
      memset(Tn, 0, sizeof(Tn));
      for (int j = 0; j <= k; ++j) {
        double v = -Tprev[j];
        if (j > 0) v += 2.0 * Tcur[j - 1];
        Tn[j] = v;
      }
      for (int j = 0; j <= k; ++j) mono[j] += cheb[k] * Tn[j];
      for (int j = 0; j <= DEG; ++j) { Tprev[j] = Tcur[j]; Tcur[j] = Tn[j]; }
    }
    for (int i = 0; i <= DEG; ++i) cf.a[i] = (float)mono[i];
    cf.cc = (float)cc; cf.inv_h = (float)(1.0 / hh);
  }

  const int nblk = nmat < GRID ? nmat : GRID;
  dim3 grid(nblk), block(256);
  hipLaunchKernelGGL(logm_kernel, grid, block, 0, stream, X, Y, nmat, cf);
}